// Round 15
// baseline (439.792 us; speedup 1.0000x reference)
//
#include <hip/hip_runtime.h>
#include <hip/hip_fp16.h>

#define THREADS 256

typedef _Float16 half8 __attribute__((ext_vector_type(8)));
typedef float f32x4 __attribute__((ext_vector_type(4)));

// ---------------- preprocessing ----------------

__global__ void k_count_dst(const int* __restrict__ ei, int* __restrict__ cnt, int E) {
    int e = blockIdx.x * blockDim.x + threadIdx.x;
    if (e < E) atomicAdd(&cnt[ei[E + e]], 1);
}

__global__ void k_count_src(const int* __restrict__ ei, int* __restrict__ cnt, int E) {
    int e = blockIdx.x * blockDim.x + threadIdx.x;
    if (e < E) atomicAdd(&cnt[ei[e]], 1);
}

__global__ void k_dinv(const int* __restrict__ cnt, float* __restrict__ dinv, int N) {
    int n = blockIdx.x * blockDim.x + threadIdx.x;
    if (n < N) dinv[n] = rsqrtf((float)cnt[n] + 1.0f);  // +1 self loop
}

__global__ void k_scan1(const int* __restrict__ cnt, int* __restrict__ rp,
                        int* __restrict__ bsum, int N) {
    __shared__ int s[THREADS];
    int tid = threadIdx.x;
    int i = blockIdx.x * THREADS + tid;
    int v = (i < N) ? cnt[i] : 0;
    s[tid] = v;
    __syncthreads();
    for (int d = 1; d < THREADS; d <<= 1) {
        int t = (tid >= d) ? s[tid - d] : 0;
        __syncthreads();
        s[tid] += t;
        __syncthreads();
    }
    if (i < N) rp[i] = s[tid] - v;
    if (tid == THREADS - 1) bsum[blockIdx.x] = s[tid];
}

__global__ void k_scan2(int* __restrict__ bsum, int nb) {
    __shared__ int s[THREADS];
    int tid = threadIdx.x;
    int v = (tid < nb) ? bsum[tid] : 0;
    s[tid] = v;
    __syncthreads();
    for (int d = 1; d < THREADS; d <<= 1) {
        int t = (tid >= d) ? s[tid - d] : 0;
        __syncthreads();
        s[tid] += t;
        __syncthreads();
    }
    if (tid < nb) bsum[tid] = s[tid] - v;
}

__global__ void k_add(int* __restrict__ rp, const int* __restrict__ bsum, int N, int E) {
    int i = blockIdx.x * THREADS + threadIdx.x;
    if (i < N) rp[i] += bsum[blockIdx.x];
    if (i == 0) rp[N] = E;
}

// dst-CSR position for each original edge
__global__ void k_scatter_d(const int* __restrict__ ei, const int* __restrict__ rp,
                            int* __restrict__ fill, int* __restrict__ dpos, int E) {
    int e = blockIdx.x * blockDim.x + threadIdx.x;
    if (e >= E) return;
    int d = ei[E + e];
    dpos[e] = rp[d] + atomicAdd(&fill[d], 1);
}

// src-CSR entries: the dst-order position this src's row must be written to
__global__ void k_scatter_s(const int* __restrict__ ei, const int* __restrict__ srp,
                            int* __restrict__ fill, const int* __restrict__ dpos,
                            int* __restrict__ sdata, int E) {
    int e = blockIdx.x * blockDim.x + threadIdx.x;
    if (e >= E) return;
    int s = ei[e];
    int sp = srp[s] + atomicAdd(&fill[s], 1);
    sdata[sp] = dpos[e];
}

// ---------------- group sizes (sorted batch, no atomics) ----------------

__global__ void k_ginit(int* __restrict__ gstart, int N, int G) {
    int g = threadIdx.x;
    if (g < G) gstart[g] = N;
}

__global__ void k_gbound(const int* __restrict__ batch, int* __restrict__ gstart, int N) {
    int n = blockIdx.x * blockDim.x + threadIdx.x;
    if (n >= N) return;
    if (n == 0) gstart[batch[0]] = 0;
    else if (batch[n] != batch[n - 1]) gstart[batch[n]] = n;
}

__global__ void k_gfix(const int* __restrict__ gstart, float* __restrict__ gcnt, int N, int G) {
    __shared__ int s[129];
    int g = threadIdx.x;
    s[g] = gstart[g];
    if (g == 0) s[128] = N;
    __syncthreads();
    for (int d = 1; d < 128; d <<= 1) {
        int v = s[g];
        int w = (g + d <= 128) ? s[g + d] : N;
        __syncthreads();
        s[g] = min(v, w);
        __syncthreads();
    }
    int nxt = (g < 127) ? s[g + 1] : N;
    gcnt[g] = (float)(nxt - s[g]);
}

// ---------------- W pre-pass: fp16 hi/lo split, transposed Wt[c][k] ----------------

__global__ void k_wcast(const float* __restrict__ W0, const float* __restrict__ W1,
                        const float* __restrict__ W2,
                        _Float16* __restrict__ Wth, _Float16* __restrict__ Wtl) {
    int idx = blockIdx.x * 256 + threadIdx.x;
    if (idx >= 3 * 16384) return;
    int m = idx >> 14;
    int rem = idx & 16383;
    int c = rem >> 7, k = rem & 127;
    const float* W = (m == 0) ? W0 : (m == 1) ? W1 : W2;
    float w = W[k * 128 + c];
    _Float16 hi = (_Float16)w;
    float lo = w - (float)hi;
    Wth[m * 16384 + c * 128 + k] = hi;
    Wtl[m * 16384 + c * 128 + k] = (_Float16)lo;
}

// ---------------- MFMA fp16 GEMM (hi/lo split) -> dinv-scaled fp16 rows ----------------

#define GBM 64

__global__ __launch_bounds__(256) void k_gemm_mfma(const float* __restrict__ X,
                                                   const _Float16* __restrict__ Wth,
                                                   const _Float16* __restrict__ Wtl,
                                                   const float* __restrict__ dinv,
                                                   _Float16* __restrict__ Yh, int N) {
    __shared__ char smem[34816];
    float*    Xs = (float*)smem;                    // [64][36]
    _Float16* Bh = (_Float16*)(smem + 9216);        // [128][40]
    _Float16* Bl = (_Float16*)(smem + 19456);       // [128][40]
    float*    Cs = (float*)smem;                    // [4][16][132]

    int tid  = threadIdx.x;
    int wid  = tid >> 6;
    int lane = tid & 63;
    int l15  = lane & 15;
    int lhi  = lane >> 4;
    int m0   = blockIdx.x * GBM;

    f32x4 acc[8];
#pragma unroll
    for (int t = 0; t < 8; ++t) acc[t] = (f32x4){0.f, 0.f, 0.f, 0.f};

    for (int k0 = 0; k0 < 128; k0 += 32) {
        __syncthreads();
#pragma unroll
        for (int i = 0; i < 2; ++i) {
            int idx = tid + 256 * i;
            int row = idx >> 3;
            int kq  = idx & 7;
            float4 v = make_float4(0.f, 0.f, 0.f, 0.f);
            if (m0 + row < N) v = *(const float4*)&X[(size_t)(m0 + row) * 128 + k0 + kq * 4];
            *(float4*)&Xs[row * 36 + kq * 4] = v;
        }
#pragma unroll
        for (int i = 0; i < 2; ++i) {
            int i4 = tid + 256 * i;
            int c  = i4 >> 2;
            int kg = i4 & 3;
            *(int4*)&Bh[c * 40 + kg * 8] = *(const int4*)&Wth[c * 128 + k0 + kg * 8];
            *(int4*)&Bl[c * 40 + kg * 8] = *(const int4*)&Wtl[c * 128 + k0 + kg * 8];
        }
        __syncthreads();

        half8 ahi, alo;
        {
            int base = (16 * wid + l15) * 36 + lhi * 8;
            float4 x0 = *(const float4*)&Xs[base];
            float4 x1 = *(const float4*)&Xs[base + 4];
            float xv[8] = {x0.x, x0.y, x0.z, x0.w, x1.x, x1.y, x1.z, x1.w};
#pragma unroll
            for (int j = 0; j < 8; ++j) {
                _Float16 h = (_Float16)xv[j];
                ahi[j] = h;
                alo[j] = (_Float16)(xv[j] - (float)h);
            }
        }
#pragma unroll
        for (int t = 0; t < 8; ++t) {
            int boff = (16 * t + l15) * 40 + lhi * 8;
            half8 bh = *(const half8*)&Bh[boff];
            half8 bl = *(const half8*)&Bl[boff];
            acc[t] = __builtin_amdgcn_mfma_f32_16x16x32_f16(ahi, bh, acc[t], 0, 0, 0);
            acc[t] = __builtin_amdgcn_mfma_f32_16x16x32_f16(alo, bh, acc[t], 0, 0, 0);
            acc[t] = __builtin_amdgcn_mfma_f32_16x16x32_f16(ahi, bl, acc[t], 0, 0, 0);
        }
    }

    __syncthreads();
    float* Cw = Cs + wid * 16 * 132;
#pragma unroll
    for (int t = 0; t < 8; ++t)
#pragma unroll
        for (int j = 0; j < 4; ++j)
            Cw[(lhi * 4 + j) * 132 + 16 * t + l15] = acc[t][j];

#pragma unroll
    for (int i = 0; i < 4; ++i) {
        int r = i * 4 + lhi;
        int rowg = m0 + 16 * wid + r;
        float4 c0 = *(const float4*)&Cw[r * 132 + l15 * 8];
        float4 c1 = *(const float4*)&Cw[r * 132 + l15 * 8 + 4];
        if (rowg < N) {
            float dv = dinv[rowg];
            __half2 p0 = __floats2half2_rn(c0.x * dv, c0.y * dv);
            __half2 p1 = __floats2half2_rn(c0.z * dv, c0.w * dv);
            __half2 p2 = __floats2half2_rn(c1.x * dv, c1.y * dv);
            __half2 p3 = __floats2half2_rn(c1.z * dv, c1.w * dv);
            int4 pk;
            pk.x = __builtin_bit_cast(int, p0);
            pk.y = __builtin_bit_cast(int, p1);
            pk.z = __builtin_bit_cast(int, p2);
            pk.w = __builtin_bit_cast(int, p3);
            *(int4*)&Yh[(size_t)rowg * 128 + l15 * 8] = pk;
        }
    }
}

// ---------------- Phase A: src-major scatter of pre-scaled rows ----------------
// wave = src node; each lane holds 16B of the row (replicated across 4 groups);
// per 4 out-edges, each 16-lane group writes one CONTIGUOUS 256B row to
// eval[dpos] (full 64B sectors -> no partial-sector amplification).

__global__ __launch_bounds__(256) void k_phaseA(const _Float16* __restrict__ Hh,
                                                const int* __restrict__ srp,
                                                const int* __restrict__ sdata,
                                                _Float16* __restrict__ eval, int N) {
    int wid  = threadIdx.x >> 6;
    int lane = threadIdx.x & 63;
    int n = blockIdx.x * 4 + wid;
    if (n >= N) return;
    int slot = lane >> 4;            // which edge of the quad this group handles
    int cg   = lane & 15;            // 16B slice of the row

    int4 rv = *(const int4*)&Hh[(size_t)n * 128 + cg * 8];

    int beg = srp[n], end = srp[n + 1];
    int last = end - 1;
    for (int e = beg; e < end; e += 4) {
        int q0 = sdata[e];
        int q1 = sdata[min(e + 1, last)];
        int q2 = sdata[min(e + 2, last)];
        int q3 = sdata[min(e + 3, last)];
        int dp = (slot & 2) ? ((slot & 1) ? q3 : q2) : ((slot & 1) ? q1 : q0);
        if (e + slot < end)
            *(int4*)&eval[(size_t)dp * 128 + cg * 8] = rv;
    }
}

// ---------------- Phase B: dst-major WIDE streaming reduce ----------------
// wave = dst node; edge rows contiguous [beg,end). Lane (rg=l>>4, cg=l&15)
// reads int4 = 16B (1KB per wave-instruction), sums 8 cols in fp32.
// Butterfly over row-groups + LDS redistribute -> coalesced finalize.

template <int POOL>
__global__ __launch_bounds__(256) void k_phaseB(const _Float16* __restrict__ Hh,
                                                const _Float16* __restrict__ eval,
                                                float* __restrict__ OUT,
                                                const int* __restrict__ rp,
                                                const float* __restrict__ dinv,
                                                const float* __restrict__ bias,
                                                const int* __restrict__ batch,
                                                float* __restrict__ pooled, int N) {
    __shared__ float sred[4][128];
    int wid  = threadIdx.x >> 6;
    int lane = threadIdx.x & 63;
    int n = blockIdx.x * 4 + wid;
    if (n >= N) return;
    int rg = lane >> 4;              // row-group 0..3
    int cg = lane & 15;              // 16B slice: cols cg*8..cg*8+7

    float a0 = 0.f, a1 = 0.f, a2 = 0.f, a3 = 0.f;
    float a4 = 0.f, a5 = 0.f, a6 = 0.f, a7 = 0.f;

    int beg = rp[n], end = rp[n + 1];

    for (int r = beg + rg; r < end; r += 4) {
        int4 v = *(const int4*)&eval[(size_t)r * 128 + cg * 8];
        float2 f;
        f = __half22float2(__builtin_bit_cast(__half2, v.x)); a0 += f.x; a1 += f.y;
        f = __half22float2(__builtin_bit_cast(__half2, v.y)); a2 += f.x; a3 += f.y;
        f = __half22float2(__builtin_bit_cast(__half2, v.z)); a4 += f.x; a5 += f.y;
        f = __half22float2(__builtin_bit_cast(__half2, v.w)); a6 += f.x; a7 += f.y;
    }

    // butterfly over the 4 row-groups
    a0 += __shfl_xor(a0, 16, 64); a0 += __shfl_xor(a0, 32, 64);
    a1 += __shfl_xor(a1, 16, 64); a1 += __shfl_xor(a1, 32, 64);
    a2 += __shfl_xor(a2, 16, 64); a2 += __shfl_xor(a2, 32, 64);
    a3 += __shfl_xor(a3, 16, 64); a3 += __shfl_xor(a3, 32, 64);
    a4 += __shfl_xor(a4, 16, 64); a4 += __shfl_xor(a4, 32, 64);
    a5 += __shfl_xor(a5, 16, 64); a5 += __shfl_xor(a5, 32, 64);
    a6 += __shfl_xor(a6, 16, 64); a6 += __shfl_xor(a6, 32, 64);
    a7 += __shfl_xor(a7, 16, 64); a7 += __shfl_xor(a7, 32, 64);

    // LDS redistribute -> full-wave coalesced finalize (R12 proven pattern)
    if (rg == 0) {
        *(float4*)&sred[wid][cg * 8]     = make_float4(a0, a1, a2, a3);
        *(float4*)&sred[wid][cg * 8 + 4] = make_float4(a4, a5, a6, a7);
    }
    asm volatile("s_waitcnt lgkmcnt(0)" ::: "memory");
    int c0 = lane * 2;
    float sx = sred[wid][c0];
    float sy = sred[wid][c0 + 1];

    float dn = dinv[n];
    float2 hv = __half22float2(*(const __half2*)&Hh[(size_t)n * 128 + c0]);
    sx = (sx + hv.x) * dn;           // (sum_src dinv[s]h[s] + dinv[n]h[n]) * dinv[n]
    sy = (sy + hv.y) * dn;
    sx = fmaxf(sx + bias[c0], 0.f);
    sy = fmaxf(sy + bias[c0 + 1], 0.f);

    if (POOL) {
        int g = batch[n];
        atomicAdd(&pooled[g * 128 + c0], sx);
        atomicAdd(&pooled[g * 128 + c0 + 1], sy);
    } else {
        float2 o; o.x = sx; o.y = sy;
        *(float2*)&OUT[(size_t)n * 128 + c0] = o;
    }
}

// ---------------- final: out[G,64] = (pooled/cnt) @ lin_W + lin_b ----------------

__global__ void k_final(const float* __restrict__ pooled, const float* __restrict__ gcnt,
                        const float* __restrict__ lw, const float* __restrict__ lb,
                        float* __restrict__ out, int G) {
    int i = blockIdx.x * blockDim.x + threadIdx.x;
    if (i >= G * 64) return;
    int g = i >> 6, o = i & 63;
    float inv = 1.0f / fmaxf(gcnt[g], 1.0f);
    float acc = 0.f;
#pragma unroll
    for (int k = 0; k < 128; ++k) acc = fmaf(pooled[g * 128 + k], lw[k * 64 + o], acc);
    out[i] = acc * inv + lb[o];
}

// ---------------- launch ----------------

extern "C" void kernel_launch(void* const* d_in, const int* in_sizes, int n_in,
                              void* d_out, int out_size, void* d_ws, size_t ws_size,
                              hipStream_t stream) {
    const float* x   = (const float*)d_in[0];
    const int* ei    = (const int*)d_in[1];
    const int* batch = (const int*)d_in[2];
    const float* W0  = (const float*)d_in[3];
    const float* b0  = (const float*)d_in[4];
    const float* W1  = (const float*)d_in[5];
    const float* b1  = (const float*)d_in[6];
    const float* W2  = (const float*)d_in[7];
    const float* b2  = (const float*)d_in[8];
    const float* lw  = (const float*)d_in[9];
    const float* lb  = (const float*)d_in[10];
    float* out = (float*)d_out;

    const int N = in_sizes[2];        // 50000
    const int E = in_sizes[1] / 2;    // 600000
    const int G = 128;

    char* ws = (char*)d_ws;
    size_t off = 0;
    auto alloc = [&](size_t bytes) -> void* {
        void* p = ws + off;
        off += (bytes + 255) & ~(size_t)255;
        return p;
    };
    float*     hA     = (float*)    alloc((size_t)N * 128 * 4);   // fp32 agg output / GEMM input
    _Float16*  hBh    = (_Float16*) alloc((size_t)N * 128 * 2);   // fp16 scaled GEMM output
    _Float16*  eval   = (_Float16*) alloc((size_t)E * 128 * 2);   // scattered edge rows (153.6MB)
    float*     dinv   = (float*)    alloc((size_t)N * 4);
    int*       cnt    = (int*)      alloc((size_t)N * 4);
    int*       cnt2   = (int*)      alloc((size_t)N * 4);
    int*       rp     = (int*)      alloc((size_t)(N + 1) * 4);
    int*       srp    = (int*)      alloc((size_t)(N + 1) * 4);
    int*       dpos   = (int*)      alloc((size_t)E * 4);
    int*       sdata  = (int*)      alloc((size_t)E * 4);
    int*       bsum   = (int*)      alloc(1024 * 4);
    float*     pooled = (float*)    alloc((size_t)G * 128 * 4);
    float*     gcnt   = (float*)    alloc((size_t)G * 4);
    int*       gstart = (int*)      alloc((size_t)(G + 1) * 4);
    _Float16*  Wth    = (_Float16*) alloc(3 * 16384 * 2);
    _Float16*  Wtl    = (_Float16*) alloc(3 * 16384 * 2);
    (void)ws_size; (void)n_in; (void)out_size;

    int nbN = (N + THREADS - 1) / THREADS;  // 196 (<=256 for k_scan2)
    int nbE = (E + THREADS - 1) / THREADS;

    hipMemsetAsync(cnt, 0, (size_t)N * 4, stream);
    hipMemsetAsync(cnt2, 0, (size_t)N * 4, stream);
    hipMemsetAsync(pooled, 0, (size_t)G * 128 * 4, stream);

    // dst CSR + per-edge dst position
    k_count_dst<<<nbE, THREADS, 0, stream>>>(ei, cnt, E);
    k_dinv<<<nbN, THREADS, 0, stream>>>(cnt, dinv, N);
    k_scan1<<<nbN, THREADS, 0, stream>>>(cnt, rp, bsum, N);
    k_scan2<<<1, THREADS, 0, stream>>>(bsum, nbN);
    k_add<<<nbN, THREADS, 0, stream>>>(rp, bsum, N, E);
    hipMemsetAsync(cnt, 0, (size_t)N * 4, stream);
    k_scatter_d<<<nbE, THREADS, 0, stream>>>(ei, rp, cnt, dpos, E);

    // src CSR with dst positions
    k_count_src<<<nbE, THREADS, 0, stream>>>(ei, cnt2, E);
    k_scan1<<<nbN, THREADS, 0, stream>>>(cnt2, srp, bsum, N);
    k_scan2<<<1, THREADS, 0, stream>>>(bsum, nbN);
    k_add<<<nbN, THREADS, 0, stream>>>(srp, bsum, N, E);
    hipMemsetAsync(cnt2, 0, (size_t)N * 4, stream);
    k_scatter_s<<<nbE, THREADS, 0, stream>>>(ei, srp, cnt2, dpos, sdata, E);

    k_ginit<<<1, 128, 0, stream>>>(gstart, N, G);
    k_gbound<<<nbN, THREADS, 0, stream>>>(batch, gstart, N);
    k_gfix<<<1, 128, 0, stream>>>(gstart, gcnt, N, G);

    k_wcast<<<(3 * 16384 + 255) / 256, 256, 0, stream>>>(W0, W1, W2, Wth, Wtl);

    int gemm_grid = (N + GBM - 1) / GBM;
    int node_grid = (N + 3) / 4;

    k_gemm_mfma<<<gemm_grid, 256, 0, stream>>>(x, Wth, Wtl, dinv, hBh, N);
    k_phaseA<<<node_grid, 256, 0, stream>>>(hBh, srp, sdata, eval, N);
    k_phaseB<0><<<node_grid, 256, 0, stream>>>(hBh, eval, hA, rp, dinv, b0, batch, pooled, N);
    k_gemm_mfma<<<gemm_grid, 256, 0, stream>>>(hA, Wth + 16384, Wtl + 16384, dinv, hBh, N);
    k_phaseA<<<node_grid, 256, 0, stream>>>(hBh, srp, sdata, eval, N);
    k_phaseB<0><<<node_grid, 256, 0, stream>>>(hBh, eval, hA, rp, dinv, b1, batch, pooled, N);
    k_gemm_mfma<<<gemm_grid, 256, 0, stream>>>(hA, Wth + 32768, Wtl + 32768, dinv, hBh, N);
    k_phaseA<<<node_grid, 256, 0, stream>>>(hBh, srp, sdata, eval, N);
    k_phaseB<1><<<node_grid, 256, 0, stream>>>(hBh, eval, hA, rp, dinv, b2, batch, pooled, N);
    k_final<<<(G * 64 + THREADS - 1) / THREADS, THREADS, 0, stream>>>(pooled, gcnt, lw, lb, out, G);
}

// Round 16
// 286.411 us; speedup vs baseline: 1.5355x; 1.5355x over previous
//
#include <hip/hip_runtime.h>
#include <hip/hip_fp16.h>

#define THREADS 256

typedef _Float16 half8 __attribute__((ext_vector_type(8)));
typedef float f32x4 __attribute__((ext_vector_type(4)));

// ---------------- preprocessing: degree, dinv, CSR build ----------------

__global__ void k_count(const int* __restrict__ ei, int* __restrict__ cnt, int E) {
    int e = blockIdx.x * blockDim.x + threadIdx.x;
    if (e < E) atomicAdd(&cnt[ei[E + e]], 1);   // dst = ei[1][e]
}

__global__ void k_dinv(const int* __restrict__ cnt, float* __restrict__ dinv, int N) {
    int n = blockIdx.x * blockDim.x + threadIdx.x;
    if (n < N) dinv[n] = rsqrtf((float)cnt[n] + 1.0f);  // +1 self loop
}

__global__ void k_scan1(const int* __restrict__ cnt, int* __restrict__ rp,
                        int* __restrict__ bsum, int N) {
    __shared__ int s[THREADS];
    int tid = threadIdx.x;
    int i = blockIdx.x * THREADS + tid;
    int v = (i < N) ? cnt[i] : 0;
    s[tid] = v;
    __syncthreads();
    for (int d = 1; d < THREADS; d <<= 1) {
        int t = (tid >= d) ? s[tid - d] : 0;
        __syncthreads();
        s[tid] += t;
        __syncthreads();
    }
    if (i < N) rp[i] = s[tid] - v;              // exclusive
    if (tid == THREADS - 1) bsum[blockIdx.x] = s[tid];
}

__global__ void k_scan2(int* __restrict__ bsum, int nb) {
    __shared__ int s[THREADS];
    int tid = threadIdx.x;
    int v = (tid < nb) ? bsum[tid] : 0;
    s[tid] = v;
    __syncthreads();
    for (int d = 1; d < THREADS; d <<= 1) {
        int t = (tid >= d) ? s[tid - d] : 0;
        __syncthreads();
        s[tid] += t;
        __syncthreads();
    }
    if (tid < nb) bsum[tid] = s[tid] - v;       // exclusive
}

__global__ void k_add(int* __restrict__ rp, const int* __restrict__ bsum, int N, int E) {
    int i = blockIdx.x * THREADS + threadIdx.x;
    if (i < N) rp[i] += bsum[blockIdx.x];
    if (i == 0) rp[N] = E;
}

// dst-sorted src stream (weight factorized out: only src index needed)
__global__ void k_scatter(const int* __restrict__ ei, const int* __restrict__ rp,
                          int* __restrict__ fill, int* __restrict__ esrc, int E) {
    int e = blockIdx.x * blockDim.x + threadIdx.x;
    if (e >= E) return;
    int s = ei[e], d = ei[E + e];
    int pos = rp[d] + atomicAdd(&fill[d], 1);
    esrc[pos] = s;
}

// ---------------- group sizes via sorted-batch boundary detection ----------------

__global__ void k_ginit(int* __restrict__ gstart, int N, int G) {
    int g = threadIdx.x;
    if (g < G) gstart[g] = N;
}

__global__ void k_gbound(const int* __restrict__ batch, int* __restrict__ gstart, int N) {
    int n = blockIdx.x * blockDim.x + threadIdx.x;
    if (n >= N) return;
    if (n == 0) gstart[batch[0]] = 0;
    else if (batch[n] != batch[n - 1]) gstart[batch[n]] = n;
}

__global__ void k_gfix(const int* __restrict__ gstart, float* __restrict__ gcnt, int N, int G) {
    __shared__ int s[129];
    int g = threadIdx.x;
    s[g] = gstart[g];
    if (g == 0) s[128] = N;
    __syncthreads();
    for (int d = 1; d < 128; d <<= 1) {
        int v = s[g];
        int w = (g + d <= 128) ? s[g + d] : N;
        __syncthreads();
        s[g] = min(v, w);
        __syncthreads();
    }
    int nxt = (g < 127) ? s[g + 1] : N;
    gcnt[g] = (float)(nxt - s[g]);
}

// ---------------- W pre-pass: fp16 hi/lo split, transposed Wt[c][k] ----------------

__global__ void k_wcast(const float* __restrict__ W0, const float* __restrict__ W1,
                        const float* __restrict__ W2,
                        _Float16* __restrict__ Wth, _Float16* __restrict__ Wtl) {
    int idx = blockIdx.x * 256 + threadIdx.x;
    if (idx >= 3 * 16384) return;
    int m = idx >> 14;
    int rem = idx & 16383;
    int c = rem >> 7, k = rem & 127;
    const float* W = (m == 0) ? W0 : (m == 1) ? W1 : W2;
    float w = W[k * 128 + c];
    _Float16 hi = (_Float16)w;
    float lo = w - (float)hi;
    Wth[m * 16384 + c * 128 + k] = hi;
    Wtl[m * 16384 + c * 128 + k] = (_Float16)lo;
}

// ---------------- MFMA fp16 GEMM (hi/lo split), writes dinv-scaled fp16 rows ----
// Yh[row] = dinv[row] * (X @ W)[row]   (weight factorization: agg sums rows
// unweighted, then multiplies by dinv[dst] once).

#define GBM 64

__global__ __launch_bounds__(256) void k_gemm_mfma(const float* __restrict__ X,
                                                   const _Float16* __restrict__ Wth,
                                                   const _Float16* __restrict__ Wtl,
                                                   const float* __restrict__ dinv,
                                                   _Float16* __restrict__ Yh, int N) {
    __shared__ char smem[34816];
    float*    Xs = (float*)smem;                    // [64][36]
    _Float16* Bh = (_Float16*)(smem + 9216);        // [128][40]
    _Float16* Bl = (_Float16*)(smem + 19456);       // [128][40]
    float*    Cs = (float*)smem;                    // [4][16][132]

    int tid  = threadIdx.x;
    int wid  = tid >> 6;
    int lane = tid & 63;
    int l15  = lane & 15;
    int lhi  = lane >> 4;                           // 0..3
    int m0   = blockIdx.x * GBM;

    f32x4 acc[8];
#pragma unroll
    for (int t = 0; t < 8; ++t) acc[t] = (f32x4){0.f, 0.f, 0.f, 0.f};

    for (int k0 = 0; k0 < 128; k0 += 32) {
        __syncthreads();
#pragma unroll
        for (int i = 0; i < 2; ++i) {
            int idx = tid + 256 * i;                // 0..511
            int row = idx >> 3;
            int kq  = idx & 7;
            float4 v = make_float4(0.f, 0.f, 0.f, 0.f);
            if (m0 + row < N) v = *(const float4*)&X[(size_t)(m0 + row) * 128 + k0 + kq * 4];
            *(float4*)&Xs[row * 36 + kq * 4] = v;
        }
#pragma unroll
        for (int i = 0; i < 2; ++i) {
            int i4 = tid + 256 * i;                 // 0..511 int4s
            int c  = i4 >> 2;
            int kg = i4 & 3;
            *(int4*)&Bh[c * 40 + kg * 8] = *(const int4*)&Wth[c * 128 + k0 + kg * 8];
            *(int4*)&Bl[c * 40 + kg * 8] = *(const int4*)&Wtl[c * 128 + k0 + kg * 8];
        }
        __syncthreads();

        half8 ahi, alo;
        {
            int base = (16 * wid + l15) * 36 + lhi * 8;
            float4 x0 = *(const float4*)&Xs[base];
            float4 x1 = *(const float4*)&Xs[base + 4];
            float xv[8] = {x0.x, x0.y, x0.z, x0.w, x1.x, x1.y, x1.z, x1.w};
#pragma unroll
            for (int j = 0; j < 8; ++j) {
                _Float16 h = (_Float16)xv[j];
                ahi[j] = h;
                alo[j] = (_Float16)(xv[j] - (float)h);
            }
        }
#pragma unroll
        for (int t = 0; t < 8; ++t) {
            int boff = (16 * t + l15) * 40 + lhi * 8;
            half8 bh = *(const half8*)&Bh[boff];
            half8 bl = *(const half8*)&Bl[boff];
            acc[t] = __builtin_amdgcn_mfma_f32_16x16x32_f16(ahi, bh, acc[t], 0, 0, 0);
            acc[t] = __builtin_amdgcn_mfma_f32_16x16x32_f16(alo, bh, acc[t], 0, 0, 0);
            acc[t] = __builtin_amdgcn_mfma_f32_16x16x32_f16(ahi, bl, acc[t], 0, 0, 0);
        }
    }

    __syncthreads();
    float* Cw = Cs + wid * 16 * 132;
#pragma unroll
    for (int t = 0; t < 8; ++t)
#pragma unroll
        for (int j = 0; j < 4; ++j)
            Cw[(lhi * 4 + j) * 132 + 16 * t + l15] = acc[t][j];

#pragma unroll
    for (int i = 0; i < 4; ++i) {
        int r = i * 4 + lhi;                        // 0..15
        int rowg = m0 + 16 * wid + r;
        float4 c0 = *(const float4*)&Cw[r * 132 + l15 * 8];
        float4 c1 = *(const float4*)&Cw[r * 132 + l15 * 8 + 4];
        if (rowg < N) {
            float dv = dinv[rowg];
            __half2 p0 = __floats2half2_rn(c0.x * dv, c0.y * dv);
            __half2 p1 = __floats2half2_rn(c0.z * dv, c0.w * dv);
            __half2 p2 = __floats2half2_rn(c1.x * dv, c1.y * dv);
            __half2 p3 = __floats2half2_rn(c1.z * dv, c1.w * dv);
            int4 pk;
            pk.x = __builtin_bit_cast(int, p0);
            pk.y = __builtin_bit_cast(int, p1);
            pk.z = __builtin_bit_cast(int, p2);
            pk.w = __builtin_bit_cast(int, p3);
            *(int4*)&Yh[(size_t)rowg * 128 + l15 * 8] = pk;
        }
    }
}

// ---------------- aggregation (R8 structure, weight-factorized) ----------------
// Hh rows are pre-scaled by dinv[src]; sum rows unweighted (0/1 mask for tail),
// add own row, multiply by dinv[dst] ONCE, + bias, relu.

template <int POOL>
__global__ __launch_bounds__(256) void k_aggregate(const __half* __restrict__ Hh,
                                                   float* __restrict__ OUT,
                                                   const int* __restrict__ rp,
                                                   const int* __restrict__ esrc,
                                                   const float* __restrict__ dinv,
                                                   const float* __restrict__ bias,
                                                   const int* __restrict__ batch,
                                                   float* __restrict__ pooled, int N) {
    int wid  = threadIdx.x >> 6;
    int lane = threadIdx.x & 63;
    int n = blockIdx.x * 4 + wid;
    if (n >= N) return;
    int c0 = lane * 2;

    float2 acc = make_float2(0.f, 0.f);
    int beg = rp[n], end = rp[n + 1];
    int last = end - 1;

    for (int e = beg; e < end; e += 8) {
        int s0 = esrc[e];
        int s1 = esrc[min(e + 1, last)];
        int s2 = esrc[min(e + 2, last)];
        int s3 = esrc[min(e + 3, last)];
        int s4 = esrc[min(e + 4, last)];
        int s5 = esrc[min(e + 5, last)];
        int s6 = esrc[min(e + 6, last)];
        int s7 = esrc[min(e + 7, last)];
        float m1 = (e + 1 < end) ? 1.f : 0.f;
        float m2 = (e + 2 < end) ? 1.f : 0.f;
        float m3 = (e + 3 < end) ? 1.f : 0.f;
        float m4 = (e + 4 < end) ? 1.f : 0.f;
        float m5 = (e + 5 < end) ? 1.f : 0.f;
        float m6 = (e + 6 < end) ? 1.f : 0.f;
        float m7 = (e + 7 < end) ? 1.f : 0.f;
        __half2 h0 = *(const __half2*)&Hh[(size_t)s0 * 128 + c0];
        __half2 h1 = *(const __half2*)&Hh[(size_t)s1 * 128 + c0];
        __half2 h2 = *(const __half2*)&Hh[(size_t)s2 * 128 + c0];
        __half2 h3 = *(const __half2*)&Hh[(size_t)s3 * 128 + c0];
        __half2 h4 = *(const __half2*)&Hh[(size_t)s4 * 128 + c0];
        __half2 h5 = *(const __half2*)&Hh[(size_t)s5 * 128 + c0];
        __half2 h6 = *(const __half2*)&Hh[(size_t)s6 * 128 + c0];
        __half2 h7 = *(const __half2*)&Hh[(size_t)s7 * 128 + c0];
        float2 f;
        f = __half22float2(h0); acc.x += f.x;                 acc.y += f.y;
        f = __half22float2(h1); acc.x = fmaf(m1, f.x, acc.x); acc.y = fmaf(m1, f.y, acc.y);
        f = __half22float2(h2); acc.x = fmaf(m2, f.x, acc.x); acc.y = fmaf(m2, f.y, acc.y);
        f = __half22float2(h3); acc.x = fmaf(m3, f.x, acc.x); acc.y = fmaf(m3, f.y, acc.y);
        f = __half22float2(h4); acc.x = fmaf(m4, f.x, acc.x); acc.y = fmaf(m4, f.y, acc.y);
        f = __half22float2(h5); acc.x = fmaf(m5, f.x, acc.x); acc.y = fmaf(m5, f.y, acc.y);
        f = __half22float2(h6); acc.x = fmaf(m6, f.x, acc.x); acc.y = fmaf(m6, f.y, acc.y);
        f = __half22float2(h7); acc.x = fmaf(m7, f.x, acc.x); acc.y = fmaf(m7, f.y, acc.y);
    }

    float dn = dinv[n];
    float2 hv = __half22float2(*(const __half2*)&Hh[(size_t)n * 128 + c0]);
    acc.x = (acc.x + hv.x) * dn;     // (sum_src dinv[s]h[s] + dinv[n]h[n]) * dinv[n]
    acc.y = (acc.y + hv.y) * dn;
    acc.x = fmaxf(acc.x + bias[c0], 0.f);
    acc.y = fmaxf(acc.y + bias[c0 + 1], 0.f);

    if (POOL) {
        int g = batch[n];
        atomicAdd(&pooled[g * 128 + c0], acc.x);
        atomicAdd(&pooled[g * 128 + c0 + 1], acc.y);
    } else {
        float2 o; o.x = acc.x; o.y = acc.y;
        *(float2*)&OUT[(size_t)n * 128 + c0] = o;
    }
}

// ---------------- final: out[G,64] = (pooled/cnt) @ lin_W + lin_b ----------------

__global__ void k_final(const float* __restrict__ pooled, const float* __restrict__ gcnt,
                        const float* __restrict__ lw, const float* __restrict__ lb,
                        float* __restrict__ out, int G) {
    int i = blockIdx.x * blockDim.x + threadIdx.x;
    if (i >= G * 64) return;
    int g = i >> 6, o = i & 63;
    float inv = 1.0f / fmaxf(gcnt[g], 1.0f);
    float acc = 0.f;
#pragma unroll
    for (int k = 0; k < 128; ++k) acc = fmaf(pooled[g * 128 + k], lw[k * 64 + o], acc);
    out[i] = acc * inv + lb[o];
}

// ---------------- launch ----------------

extern "C" void kernel_launch(void* const* d_in, const int* in_sizes, int n_in,
                              void* d_out, int out_size, void* d_ws, size_t ws_size,
                              hipStream_t stream) {
    const float* x   = (const float*)d_in[0];
    const int* ei    = (const int*)d_in[1];
    const int* batch = (const int*)d_in[2];
    const float* W0  = (const float*)d_in[3];
    const float* b0  = (const float*)d_in[4];
    const float* W1  = (const float*)d_in[5];
    const float* b1  = (const float*)d_in[6];
    const float* W2  = (const float*)d_in[7];
    const float* b2  = (const float*)d_in[8];
    const float* lw  = (const float*)d_in[9];
    const float* lb  = (const float*)d_in[10];
    float* out = (float*)d_out;

    const int N = in_sizes[2];        // 50000
    const int E = in_sizes[1] / 2;    // 600000
    const int G = 128;

    char* ws = (char*)d_ws;
    size_t off = 0;
    auto alloc = [&](size_t bytes) -> void* {
        void* p = ws + off;
        off += (bytes + 255) & ~(size_t)255;
        return p;
    };
    float*     hA     = (float*)    alloc((size_t)N * 128 * 4);   // fp32 agg output / GEMM input
    _Float16*  hBh    = (_Float16*) alloc((size_t)N * 128 * 2);   // fp16 scaled GEMM output
    float*     dinv   = (float*)    alloc((size_t)N * 4);
    int*       cnt    = (int*)      alloc((size_t)N * 4);
    int*       rp     = (int*)      alloc((size_t)(N + 1) * 4);
    int*       esrc   = (int*)      alloc((size_t)E * 4);
    int*       bsum   = (int*)      alloc(1024 * 4);
    float*     pooled = (float*)    alloc((size_t)G * 128 * 4);
    float*     gcnt   = (float*)    alloc((size_t)G * 4);
    int*       gstart = (int*)      alloc((size_t)(G + 1) * 4);
    _Float16*  Wth    = (_Float16*) alloc(3 * 16384 * 2);
    _Float16*  Wtl    = (_Float16*) alloc(3 * 16384 * 2);
    (void)ws_size; (void)n_in; (void)out_size;

    int nbN = (N + THREADS - 1) / THREADS;  // 196 (<=256 for k_scan2)
    int nbE = (E + THREADS - 1) / THREADS;

    hipMemsetAsync(cnt, 0, (size_t)N * 4, stream);
    hipMemsetAsync(pooled, 0, (size_t)G * 128 * 4, stream);

    k_count<<<nbE, THREADS, 0, stream>>>(ei, cnt, E);
    k_dinv<<<nbN, THREADS, 0, stream>>>(cnt, dinv, N);
    k_scan1<<<nbN, THREADS, 0, stream>>>(cnt, rp, bsum, N);
    k_scan2<<<1, THREADS, 0, stream>>>(bsum, nbN);
    k_add<<<nbN, THREADS, 0, stream>>>(rp, bsum, N, E);
    hipMemsetAsync(cnt, 0, (size_t)N * 4, stream);   // reuse as fill counters
    k_scatter<<<nbE, THREADS, 0, stream>>>(ei, rp, cnt, esrc, E);

    k_ginit<<<1, 128, 0, stream>>>(gstart, N, G);
    k_gbound<<<nbN, THREADS, 0, stream>>>(batch, gstart, N);
    k_gfix<<<1, 128, 0, stream>>>(gstart, gcnt, N, G);

    k_wcast<<<(3 * 16384 + 255) / 256, 256, 0, stream>>>(W0, W1, W2, Wth, Wtl);

    int gemm_grid = (N + GBM - 1) / GBM;
    int node_grid = (N + 3) / 4;
    const __half* HhR = (const __half*)hBh;

    k_gemm_mfma<<<gemm_grid, 256, 0, stream>>>(x, Wth, Wtl, dinv, hBh, N);
    k_aggregate<0><<<node_grid, 256, 0, stream>>>(HhR, hA, rp, esrc, dinv, b0, batch, pooled, N);
    k_gemm_mfma<<<gemm_grid, 256, 0, stream>>>(hA, Wth + 16384, Wtl + 16384, dinv, hBh, N);
    k_aggregate<0><<<node_grid, 256, 0, stream>>>(HhR, hA, rp, esrc, dinv, b1, batch, pooled, N);
    k_gemm_mfma<<<gemm_grid, 256, 0, stream>>>(hA, Wth + 32768, Wtl + 32768, dinv, hBh, N);
    k_aggregate<1><<<node_grid, 256, 0, stream>>>(HhR, hA, rp, esrc, dinv, b2, batch, pooled, N);
    k_final<<<(G * 64 + THREADS - 1) / THREADS, THREADS, 0, stream>>>(pooled, gcnt, lw, lb, out, G);
}